// Round 7
// baseline (290.816 us; speedup 1.0000x reference)
//
#include <hip/hip_runtime.h>
#include <hip/hip_bf16.h>

#define T_DIM 1024
#define B_DIM 4
#define E_DIM 1024
#define H_DIM 16
#define HD    64
#define M_DIM (T_DIM * B_DIM)   // 4096

typedef __hip_bfloat16 bf16;
typedef __bf16 bf16x8 __attribute__((ext_vector_type(8)));
typedef __bf16 bf16x4 __attribute__((ext_vector_type(4)));
typedef float  f32x4  __attribute__((ext_vector_type(4)));

#define P4S ((size_t)M_DIM * E_DIM)   // 4194304
#define P1S ((size_t)E_DIM * E_DIM)   // 1048576

// log2(e)-folded Gaussian constants: exp(-c*d) = 2^(-C*d), C = c*log2(e)
#define C1F 0.0901684437f   // 0.0625 * 1.44269504
#define C2F 0.2705053270f   // 0.1875 * 1.44269504

// ------------------------------------------- fused f32 -> bf16 (all 8 buffers)
__global__ __launch_bounds__(256) void cvt_all(
    const float* __restrict__ q, const float* __restrict__ k,
    const float* __restrict__ v, const float* __restrict__ w0,
    const float* __restrict__ w1, const float* __restrict__ w2,
    const float* __restrict__ w3, const float* __restrict__ w4,
    __bf16* __restrict__ dst)
{
  size_t i = ((size_t)blockIdx.x * 256 + threadIdx.x) * 8;
  const float* src;
  size_t off;
  if (i < P4S)            { src = q; off = i; }
  else if (i < 2 * P4S)   { src = k; off = i - P4S; }
  else if (i < 3 * P4S)   { src = v; off = i - 2 * P4S; }
  else {
    size_t j = i - 3 * P4S;
    int wsel = (int)(j >> 20);
    off = j & (P1S - 1);
    const float* ws[5] = {w0, w1, w2, w3, w4};
    src = ws[wsel];
  }
  float4 a = *(const float4*)(src + off);
  float4 b = *(const float4*)(src + off + 4);
  bf16x8 o;
  o[0] = (__bf16)a.x; o[1] = (__bf16)a.y; o[2] = (__bf16)a.z; o[3] = (__bf16)a.w;
  o[4] = (__bf16)b.x; o[5] = (__bf16)b.y; o[6] = (__bf16)b.z; o[7] = (__bf16)b.w;
  *(bf16x8*)(dst + i) = o;
}

// ------------------------------------------------- async global->LDS, 16 B/lane
__device__ __forceinline__ void load_lds16(const __bf16* g, __bf16* l) {
  __builtin_amdgcn_global_load_lds(
      (__attribute__((address_space(1))) void*)(void*)g,
      (__attribute__((address_space(3))) void*)l, 16, 0, 0);
}

// --------------------------------------------------- GEMM core (128x128, BK=32)
template <typename TO>
__device__ __forceinline__ void gemm_body(
    const __bf16* __restrict__ X, const __bf16* __restrict__ W,
    const float* __restrict__ bias, TO* __restrict__ C,
    int bm, int bn, int Ndim, int Kdim, __bf16* As, __bf16* Bs)
{
  const int tid  = threadIdx.x;
  const int lane = tid & 63;
  const int wave = tid >> 6;
  const int wy = (wave >> 1) * 64;
  const int wx = (wave & 1) * 64;
  const int mrow = lane & 15, quad = lane >> 4;

  const int srow = tid >> 2;
  const int ke   = (tid & 3) * 8;
  const __bf16* gA0 = X + (size_t)(bm + srow)      * Kdim + ke;
  const __bf16* gA1 = X + (size_t)(bm + srow + 64) * Kdim + ke;
  const __bf16* gB0 = W + (size_t)(bn + srow)      * Kdim + ke;
  const __bf16* gB1 = W + (size_t)(bn + srow + 64) * Kdim + ke;
  __bf16* lA0 = As + tid * 8;
  __bf16* lA1 = As + (tid + 256) * 8;
  __bf16* lB0 = Bs + tid * 8;
  __bf16* lB1 = Bs + (tid + 256) * 8;

  f32x4 acc[4][4];
#pragma unroll
  for (int i = 0; i < 4; ++i)
#pragma unroll
    for (int j = 0; j < 4; ++j) acc[i][j] = (f32x4)0.0f;

  for (int k0 = 0; k0 < Kdim; k0 += 32) {
    __syncthreads();
    load_lds16(gA0 + k0, lA0);
    load_lds16(gA1 + k0, lA1);
    load_lds16(gB0 + k0, lB0);
    load_lds16(gB1 + k0, lB1);
    __syncthreads();
    bf16x8 af[4], bf[4];
#pragma unroll
    for (int i = 0; i < 4; ++i)
      af[i] = *(const bf16x8*)(As + (wy + i * 16 + mrow) * 32 + quad * 8);
#pragma unroll
    for (int j = 0; j < 4; ++j)
      bf[j] = *(const bf16x8*)(Bs + (wx + j * 16 + mrow) * 32 + quad * 8);
#pragma unroll
    for (int i = 0; i < 4; ++i)
#pragma unroll
      for (int j = 0; j < 4; ++j)
        acc[i][j] = __builtin_amdgcn_mfma_f32_16x16x32_bf16(af[i], bf[j], acc[i][j], 0, 0, 0);
  }

#pragma unroll
  for (int j = 0; j < 4; ++j) {
    int col = bn + wx + j * 16 + mrow;
    float bc = bias[col];
#pragma unroll
    for (int i = 0; i < 4; ++i) {
      int rbase = bm + wy + i * 16 + quad * 4;
#pragma unroll
      for (int r = 0; r < 4; ++r)
        C[(size_t)(rbase + r) * Ndim + col] = (TO)(acc[i][j][r] + bc);
    }
  }
}

// All four projection GEMMs in one dispatch; z picks {q,k1,k2,v}.
__global__ __launch_bounds__(256) void proj_gemm4(
    const __bf16* __restrict__ xbase, const __bf16* __restrict__ wbase,
    const float* __restrict__ bin, __bf16* __restrict__ cbase)
{
  __shared__ __bf16 As[128 * 32];
  __shared__ __bf16 Bs[128 * 32];
  const int z = blockIdx.z;
  const __bf16* X = xbase + ((z == 0) ? 0 : (z == 3) ? 2 * P4S : P4S);
  const __bf16* W = wbase + (size_t)z * P1S;
  const float* bias = bin + z * E_DIM;
  __bf16* C = cbase + (size_t)z * P4S;
  gemm_body<__bf16>(X, W, bias, C, blockIdx.x * 128, blockIdx.y * 128,
                    E_DIM, E_DIM, As, Bs);
}

// Output projection, split-K=2 (z = K half), atomicAdd into bias-prefilled out.
__global__ __launch_bounds__(256) void out_gemm_sk(
    const __bf16* __restrict__ X, const __bf16* __restrict__ W,
    float* __restrict__ C)
{
  __shared__ __bf16 As[128 * 32];
  __shared__ __bf16 Bs[128 * 32];
  const int tid  = threadIdx.x;
  const int lane = tid & 63;
  const int wave = tid >> 6;
  const int wy = (wave >> 1) * 64;
  const int wx = (wave & 1) * 64;
  const int bm = blockIdx.x * 128, bn = blockIdx.y * 128;
  const int kbeg = blockIdx.z * 512;
  const int mrow = lane & 15, quad = lane >> 4;

  const int srow = tid >> 2;
  const int ke   = (tid & 3) * 8;
  const __bf16* gA0 = X + (size_t)(bm + srow)      * E_DIM + kbeg + ke;
  const __bf16* gA1 = X + (size_t)(bm + srow + 64) * E_DIM + kbeg + ke;
  const __bf16* gB0 = W + (size_t)(bn + srow)      * E_DIM + kbeg + ke;
  const __bf16* gB1 = W + (size_t)(bn + srow + 64) * E_DIM + kbeg + ke;
  __bf16* lA0 = As + tid * 8;
  __bf16* lA1 = As + (tid + 256) * 8;
  __bf16* lB0 = Bs + tid * 8;
  __bf16* lB1 = Bs + (tid + 256) * 8;

  f32x4 acc[4][4];
#pragma unroll
  for (int i = 0; i < 4; ++i)
#pragma unroll
    for (int j = 0; j < 4; ++j) acc[i][j] = (f32x4)0.0f;

  for (int k0 = 0; k0 < 512; k0 += 32) {
    __syncthreads();
    load_lds16(gA0 + k0, lA0);
    load_lds16(gA1 + k0, lA1);
    load_lds16(gB0 + k0, lB0);
    load_lds16(gB1 + k0, lB1);
    __syncthreads();
    bf16x8 af[4], bf[4];
#pragma unroll
    for (int i = 0; i < 4; ++i)
      af[i] = *(const bf16x8*)(As + (wy + i * 16 + mrow) * 32 + quad * 8);
#pragma unroll
    for (int j = 0; j < 4; ++j)
      bf[j] = *(const bf16x8*)(Bs + (wx + j * 16 + mrow) * 32 + quad * 8);
#pragma unroll
    for (int i = 0; i < 4; ++i)
#pragma unroll
      for (int j = 0; j < 4; ++j)
        acc[i][j] = __builtin_amdgcn_mfma_f32_16x16x32_bf16(af[i], bf[j], acc[i][j], 0, 0, 0);
  }

#pragma unroll
  for (int j = 0; j < 4; ++j) {
    int col = bn + wx + j * 16 + mrow;
#pragma unroll
    for (int i = 0; i < 4; ++i) {
      int rbase = bm + wy + i * 16 + quad * 4;
#pragma unroll
      for (int r = 0; r < 4; ++r)
        unsafeAtomicAdd(&C[(size_t)(rbase + r) * E_DIM + col], acc[i][j][r]);
    }
  }
}

// ---------------- prep: norms (folded) + V transpose + bias prefill, one dispatch
// blocks [0,768): qn raw / kn1' = C1*kn1 - log2(p1) / kn2' = C2*kn2 - log2(p2)
// blocks [768,1792): Vt_g[bh][d][kt*64+u] = V[kt*64+sigma(u)][d], sigma(u)=(u&3)*16+(u>>2)
// blocks [1792,2816): out[i] = bo[i & 1023]
__global__ __launch_bounds__(256) void prep(
    const __bf16* __restrict__ Qp, const __bf16* __restrict__ K1p,
    const __bf16* __restrict__ K2p, const __bf16* __restrict__ Vp,
    const float* __restrict__ pi, const float* __restrict__ bo,
    float* __restrict__ qn, float* __restrict__ kn1, float* __restrict__ kn2,
    __bf16* __restrict__ Vt_g, float* __restrict__ out)
{
  const int bid = blockIdx.x, tid = threadIdx.x;
  if (bid < 768) {
    int id = bid * 256 + tid;
    int which = id >> 16;
    int r = id & 65535;
    int bh = r >> 10, t = r & 1023;
    int b = bh >> 4, h = bh & 15;
    const __bf16* src = (which == 0) ? Qp : ((which == 1) ? K1p : K2p);
    const __bf16* p = src + (size_t)(t * 4 + b) * 1024 + h * 64;
    float s = 0.f;
#pragma unroll
    for (int c = 0; c < 8; ++c) {
      bf16x8 v = *(const bf16x8*)(p + c * 8);
#pragma unroll
      for (int j = 0; j < 8; ++j) { float x = (float)v[j]; s += x * x; }
    }
    if (which == 0) {
      qn[bh * 1024 + t] = s;
    } else if (which == 1) {
      float p1 = fminf(fmaxf(fabsf(pi[h]), 1e-6f), 2.0f);
      kn1[bh * 1024 + t] = C1F * s - __builtin_amdgcn_logf(p1);
    } else {
      float p2 = fminf(fmaxf(fabsf(pi[H_DIM + h]), 1e-6f), 2.0f);
      kn2[bh * 1024 + t] = C2F * s - __builtin_amdgcn_logf(p2);
    }
  } else if (bid < 1792) {
    int idx = bid - 768;
    int bh = idx >> 4, kt = idx & 15;
    int b = bh >> 4, h = bh & 15;
    __shared__ __bf16 tile[64][88];
    {
      int s = tid >> 2, d0 = (tid & 3) * 16;
      const __bf16* src = Vp + (size_t)((kt * 64 + s) * 4 + b) * 1024 + h * 64 + d0;
      *(bf16x8*)(&tile[s][d0])     = *(const bf16x8*)(src);
      *(bf16x8*)(&tile[s][d0 + 8]) = *(const bf16x8*)(src + 8);
    }
    __syncthreads();
#pragma unroll
    for (int c = 0; c < 2; ++c) {
      int idx2 = tid * 2 + c;
      int d = idx2 >> 3, u0 = (idx2 & 7) * 8;
      bf16x8 o;
#pragma unroll
      for (int i = 0; i < 8; ++i) {
        int u = u0 + i;
        int s = (u & 3) * 16 + (u >> 2);
        o[i] = tile[s][d];
      }
      *(bf16x8*)(Vt_g + ((size_t)bh * 64 + d) * 1024 + kt * 64 + u0) = o;
    }
  } else {
    int idx = (bid - 1792) * 256 + tid;
    int base = idx * 16;
#pragma unroll
    for (int c = 0; c < 4; ++c)
      *(float4*)(out + base + c * 4) = *(const float4*)(bo + ((base + c * 4) & 1023));
  }
}

// -------------------------------------------------------- MFMA flash attention
// block = (bh, qt): 128 q-rows; 4 waves x 32 q-rows. 64-key tiles.
// Prefetch structure: [ready] -> frag reads -> [reads-done] -> stage kt+1 -> compute.
// Pl is wave-private (no barrier). Q fragments hoisted (loop-invariant).
__global__ __launch_bounds__(256, 2) void mgk_attn_mfma(
    const __bf16* __restrict__ Qp, const __bf16* __restrict__ K1p,
    const __bf16* __restrict__ K2p, const __bf16* __restrict__ Vt_g,
    const float* __restrict__ qn_g, const float* __restrict__ kn1_g,
    const float* __restrict__ kn2_g, __bf16* __restrict__ AO)
{
  __shared__ __bf16 lds[28672];          // 56 KB
  __bf16* Qs  = lds;                     // 128x64
  __bf16* K1s = lds + 8192;              // 64x64
  __bf16* K2s = lds + 12288;             // 64x64
  __bf16* Vt  = lds + 16384;             // 64(d) x 64(u)
  __bf16* Pl  = lds + 20480;             // 4 waves x 32(q) x 64(u)

  const int bh = blockIdx.x, qt = blockIdx.y;
  const int b = bh >> 4, h = bh & 15;
  const int tid = threadIdx.x, lane = tid & 63, w = tid >> 6;
  const int mrow = lane & 15, quad = lane >> 4;
  const int hoff = h * 64;

  const float TWO_C1 = 2.0f * C1F, TWO_C2 = 2.0f * C2F;

  // per-lane row norms (loop-invariant), pre-scaled
  f32x4 s1v[2], s2v[2];
#pragma unroll
  for (int i = 0; i < 2; ++i) {
    f32x4 q = *(const f32x4*)(qn_g + bh * 1024 + qt * 128 + w * 32 + i * 16 + quad * 4);
    s1v[i] = C1F * q;
    s2v[i] = C2F * q;
  }

  // ---- staging helpers ----
  auto stageK = [&](int kt) {
#pragma unroll
    for (int wi = 0; wi < 2; ++wi) {
      int window = w * 2 + wi;
      int kr = window * 8 + (lane >> 3), c = lane & 7;
      size_t srow = (size_t)((kt * 64 + kr) * 4 + b) * 1024 + hoff;
      int off = (c ^ (kr & 7)) << 3;
      load_lds16(K1p + srow + off, K1s + window * 512 + lane * 8);
      load_lds16(K2p + srow + off, K2s + window * 512 + lane * 8);
      load_lds16(Vt_g + ((size_t)bh * 64 + kr) * 1024 + kt * 64 + off,
                 Vt + window * 512 + lane * 8);
    }
  };

  // stage Q (once) + K tiles for kt=0
#pragma unroll
  for (int wi = 0; wi < 4; ++wi) {
    int window = w * 4 + wi;
    int qr = window * 8 + (lane >> 3), c = lane & 7;
    const __bf16* src = Qp + (size_t)((qt * 128 + qr) * 4 + b) * 1024 + hoff
                        + ((c ^ (qr & 7)) << 3);
    load_lds16(src, Qs + window * 512 + lane * 8);
  }
  stageK(0);

  f32x4 oacc[2][4];
#pragma unroll
  for (int i = 0; i < 2; ++i)
#pragma unroll
    for (int j = 0; j < 4; ++j) oacc[i][j] = (f32x4)0.0f;
  f32x4 rsl[2] = {(f32x4)0.0f, (f32x4)0.0f};

  __syncthreads();                                 // Q + K(0) staged

  // Q fragments: loop-invariant
  bf16x8 af[2][2];
#pragma unroll
  for (int i = 0; i < 2; ++i)
#pragma unroll
    for (int kk = 0; kk < 2; ++kk)
      af[i][kk] = *(const bf16x8*)(Qs + (w * 32 + i * 16 + mrow) * 64
                                   + (((kk * 4 + quad) ^ (mrow & 7)) << 3));

  for (int kt = 0; kt < 16; ++kt) {
    // folded key norms for this tile (global, independent of LDS)
    float kn1j[4], kn2j[4];
#pragma unroll
    for (int j = 0; j < 4; ++j) {
      kn1j[j] = kn1_g[bh * 1024 + kt * 64 + j * 16 + mrow];
      kn2j[j] = kn2_g[bh * 1024 + kt * 64 + j * 16 + mrow];
    }

    // fragment reads of shared tiles
    bf16x8 b1f[2][4], b2f[2][4], vf[2][4];
#pragma unroll
    for (int kk = 0; kk < 2; ++kk)
#pragma unroll
      for (int j = 0; j < 4; ++j) {
        int off = (j * 16 + mrow) * 64 + (((kk * 4 + quad) ^ (mrow & 7)) << 3);
        b1f[kk][j] = *(const bf16x8*)(K1s + off);
        b2f[kk][j] = *(const bf16x8*)(K2s + off);
        vf[kk][j]  = *(const bf16x8*)(Vt  + off);
      }
    __syncthreads();                               // all waves done reading tiles

    if (kt < 15) stageK(kt + 1);                   // async; overlaps compute below

    // ---- S1, S2 via MFMA ----
    f32x4 acc1[2][4], acc2[2][4];
#pragma unroll
    for (int i = 0; i < 2; ++i)
#pragma unroll
      for (int j = 0; j < 4; ++j) { acc1[i][j] = (f32x4)0.0f; acc2[i][j] = (f32x4)0.0f; }
#pragma unroll
    for (int kk = 0; kk < 2; ++kk)
#pragma unroll
      for (int j = 0; j < 4; ++j)
#pragma unroll
        for (int i = 0; i < 2; ++i) {
          acc1[i][j] = __builtin_amdgcn_mfma_f32_16x16x32_bf16(af[i][kk], b1f[kk][j], acc1[i][j], 0, 0, 0);
          acc2[i][j] = __builtin_amdgcn_mfma_f32_16x16x32_bf16(af[i][kk], b2f[kk][j], acc2[i][j], 0, 0, 0);
        }

    // ---- P = 2^(2C1*dot - s1 - kn1') + 2^(2C2*dot - s2 - kn2'); Pl (sigma order)
#pragma unroll
    for (int i = 0; i < 2; ++i) {
      f32x4 pv[4];
#pragma unroll
      for (int j = 0; j < 4; ++j) {
        f32x4 d1 = s1v[i] + kn1j[j];
        f32x4 d2 = s2v[i] + kn2j[j];
        f32x4 p;
#pragma unroll
        for (int r = 0; r < 4; ++r)
          p[r] = __builtin_amdgcn_exp2f(TWO_C1 * acc1[i][j][r] - d1[r])
               + __builtin_amdgcn_exp2f(TWO_C2 * acc2[i][j][r] - d2[r]);
        pv[j] = p;
        rsl[i] += p;
      }
#pragma unroll
      for (int r = 0; r < 4; ++r) {
        int q = i * 16 + quad * 4 + r;
        bf16x4 pk;
        pk[0] = (__bf16)pv[0][r]; pk[1] = (__bf16)pv[1][r];
        pk[2] = (__bf16)pv[2][r]; pk[3] = (__bf16)pv[3][r];
        int lc = mrow >> 1;
        *(bf16x4*)(Pl + w * 2048 + q * 64 + ((lc ^ (q & 7)) << 3) + (mrow & 1) * 4) = pk;
      }
    }

    // ---- O += P * V (Pl wave-private: lgkmcnt handles write->read) ----
    bf16x8 pf[2][2];
#pragma unroll
    for (int i = 0; i < 2; ++i)
#pragma unroll
      for (int kk = 0; kk < 2; ++kk)
        pf[i][kk] = *(const bf16x8*)(Pl + w * 2048 + (i * 16 + mrow) * 64
                                     + (((kk * 4 + quad) ^ (mrow & 7)) << 3));
#pragma unroll
    for (int kk = 0; kk < 2; ++kk)
#pragma unroll
      for (int j = 0; j < 4; ++j)
#pragma unroll
        for (int i = 0; i < 2; ++i)
          oacc[i][j] = __builtin_amdgcn_mfma_f32_16x16x32_bf16(pf[i][kk], vf[kk][j], oacc[i][j], 0, 0, 0);

    if (kt < 15) __syncthreads();                  // staged kt+1 ready (vmcnt drain)
  }

  // rowsum butterfly across 16 lanes (mrow)
#pragma unroll
  for (int i = 0; i < 2; ++i)
#pragma unroll
    for (int d = 1; d < 16; d <<= 1) {
      f32x4 o;
#pragma unroll
      for (int r = 0; r < 4; ++r) o[r] = __shfl_xor(rsl[i][r], d, 64);
      rsl[i] += o;
    }

  // normalize + write AO (M,E) bf16
#pragma unroll
  for (int i = 0; i < 2; ++i) {
    f32x4 inv;
#pragma unroll
    for (int r = 0; r < 4; ++r) inv[r] = 1.0f / (rsl[i][r] + 1e-6f);
#pragma unroll
    for (int j = 0; j < 4; ++j) {
      int col = hoff + j * 16 + mrow;
#pragma unroll
      for (int r = 0; r < 4; ++r) {
        int t = qt * 128 + w * 32 + i * 16 + quad * 4 + r;
        AO[(size_t)(t * 4 + b) * 1024 + col] = (__bf16)(oacc[i][j][r] * inv[r]);
      }
    }
  }
}

extern "C" void kernel_launch(void* const* d_in, const int* in_sizes, int n_in,
                              void* d_out, int out_size, void* d_ws, size_t ws_size,
                              hipStream_t stream) {
  const float* query = (const float*)d_in[0];
  const float* key   = (const float*)d_in[1];
  const float* value = (const float*)d_in[2];
  const float* Wq    = (const float*)d_in[3];
  const float* Wk1   = (const float*)d_in[4];
  const float* Wk2   = (const float*)d_in[5];
  const float* Wv    = (const float*)d_in[6];
  const float* bin   = (const float*)d_in[7];
  const float* Wo    = (const float*)d_in[8];
  const float* bo    = (const float*)d_in[9];
  const float* pi    = (const float*)d_in[10];
  float* out = (float*)d_out;

  __bf16* qc  = (__bf16*)d_ws;          // 3*P4: qc|kc|vc
  __bf16* wq  = qc  + 3 * P4S;          // 5*P1: wq|wk1|wk2|wv|wo
  __bf16* wo  = wq  + 4 * P1S;
  __bf16* Qp  = wq  + 5 * P1S;          // 4*P4: Qp|K1p|K2p|Vp
  __bf16* K1p = Qp  + P4S;
  __bf16* K2p = K1p + P4S;
  __bf16* Vp  = K2p + P4S;
  __bf16* AO  = Vp  + P4S;
  float*  qn_g  = (float*)(AO + P4S);
  float*  kn1_g = qn_g  + 64 * 1024;
  float*  kn2_g = kn1_g + 64 * 1024;
  __bf16* Vt_g  = qc;                   // reuse: qc dead after proj_gemm4

  cvt_all<<<8704, 256, 0, stream>>>(query, key, value, Wq, Wk1, Wk2, Wv, Wo, qc);

  proj_gemm4<<<dim3(M_DIM / 128, E_DIM / 128, 4), 256, 0, stream>>>(qc, wq, bin, Qp);

  prep<<<2816, 256, 0, stream>>>(Qp, K1p, K2p, Vp, pi, bo,
                                 qn_g, kn1_g, kn2_g, Vt_g, out);

  mgk_attn_mfma<<<dim3(64, 8), 256, 0, stream>>>(
      Qp, K1p, K2p, Vt_g, qn_g, kn1_g, kn2_g, AO);

  out_gemm_sk<<<dim3(M_DIM / 128, E_DIM / 128, 2), 256, 0, stream>>>(AO, wo, out);
}